// Round 1
// baseline (484.594 us; speedup 1.0000x reference)
//
#include <hip/hip_runtime.h>
#include <stdint.h>

// Problem constants (reference: rec_audio (256, 131072) f32, k = int(0.03*131072) = 3932)
#define NROWS 256
#define NCOLS 131072
#define KSEL  3932
#define TPB   1024
#define BINS  8192          // histogram over top 13 bits of the 23-bit mantissa value
#define MAXC  2048          // candidate-list capacity (expected ~16 per row)

__device__ __forceinline__ uint32_t rotl32(uint32_t v, int r) {
    return (v << r) | (v >> (32 - r));
}

// JAX threefry2x32 with key (0, 42); partitionable random-bits scheme:
// counter = (uint64)j  ->  x0 = hi32 = 0, x1 = lo32 = j;  bits32 = out0 ^ out1.
__device__ __forceinline__ uint32_t jax_bits(uint32_t j) {
    const uint32_t ks0 = 0u;
    const uint32_t ks1 = 42u;
    const uint32_t ks2 = ks0 ^ ks1 ^ 0x1BD11BDAu;
    uint32_t x0 = 0u + ks0;
    uint32_t x1 = j + ks1;
#define TF_RND(r) { x0 += x1; x1 = rotl32(x1, r); x1 ^= x0; }
    TF_RND(13) TF_RND(15) TF_RND(26) TF_RND(6)
    x0 += ks1; x1 += ks2 + 1u;
    TF_RND(17) TF_RND(29) TF_RND(16) TF_RND(24)
    x0 += ks2; x1 += ks0 + 2u;
    TF_RND(13) TF_RND(15) TF_RND(26) TF_RND(6)
    x0 += ks0; x1 += ks1 + 3u;
    TF_RND(17) TF_RND(29) TF_RND(16) TF_RND(24)
    x0 += ks1; x1 += ks2 + 4u;
    TF_RND(13) TF_RND(15) TF_RND(26) TF_RND(6)
    x0 += ks2; x1 += ks0 + 5u;
#undef TF_RND
    return x0 ^ x1;
}

// m = 23-bit value whose ordering equals the ordering of jax.random.uniform output
__device__ __forceinline__ uint32_t jax_m(uint32_t j) {
    return jax_bits(j) >> 9;
}

__global__ __launch_bounds__(TPB) void topk_mask_kernel(const float* __restrict__ in,
                                                        float* __restrict__ out) {
    __shared__ uint32_t hist[BINS];          // 32 KB
    __shared__ uint32_t chunkInfo[TPB];      // 4 KB: chunk sums, then "count above chunk"
    __shared__ uint32_t ckeys[MAXC];         // 8 KB
    __shared__ uint32_t s_ccount;
    __shared__ uint32_t s_bstar;
    __shared__ uint32_t s_r;
    __shared__ uint32_t s_tkey;

    const uint32_t row  = blockIdx.x;
    const uint32_t tid  = threadIdx.x;
    const uint32_t base = row * (uint32_t)NCOLS;

    for (uint32_t i = tid; i < BINS; i += TPB) hist[i] = 0u;
    if (tid == 0) s_ccount = 0u;
    __syncthreads();

    // ---- Phase A: coarse histogram over m >> 10 ----
    for (int it = 0; it < NCOLS / TPB; ++it) {
        uint32_t c = tid + it * TPB;
        uint32_t m = jax_m(base + c);
        atomicAdd(&hist[m >> 10], 1u);
    }
    __syncthreads();

    // per-thread chunk sums (8 bins each)
    uint32_t cs = 0;
    #pragma unroll
    for (int b = 0; b < BINS / TPB; ++b) cs += hist[tid * (BINS / TPB) + b];
    chunkInfo[tid] = cs;
    __syncthreads();

    // serial suffix scan over 1024 chunks (top bin = largest value)
    if (tid == 0) {
        uint32_t acc = 0;
        for (int t = TPB - 1; t >= 0; --t) {
            uint32_t above = acc;
            acc += chunkInfo[t];
            chunkInfo[t] = above;            // now: count of elements in bins above this chunk
        }
    }
    __syncthreads();

    uint32_t above = chunkInfo[tid];
    if (above < KSEL && above + cs >= KSEL) {      // boundary bin is in my chunk (exactly one thread)
        uint32_t acc2 = above;
        for (int b = BINS / TPB - 1; b >= 0; --b) {
            uint32_t bin = tid * (BINS / TPB) + b;
            uint32_t h = hist[bin];
            if (acc2 < KSEL && acc2 + h >= KSEL) {
                s_bstar = bin;
                s_r = KSEL - acc2;           // how many to take from the boundary bin
            }
            acc2 += h;
        }
    }
    __syncthreads();

    const uint32_t bstar = s_bstar;
    const uint32_t r     = s_r;

    // ---- Phase B: collect candidates in boundary bin ----
    for (int it = 0; it < NCOLS / TPB; ++it) {
        uint32_t c = tid + it * TPB;
        uint32_t m = jax_m(base + c);
        if ((m >> 10) == bstar) {
            uint32_t pos = atomicAdd(&s_ccount, 1u);
            if (pos < MAXC)
                ckeys[pos] = ((m & 1023u) << 17) | (131071u - c);  // value desc, index asc
        }
    }
    __syncthreads();

    if (tid == 0) {
        uint32_t cc = s_ccount; if (cc > MAXC) cc = MAXC;
        // insertion sort, descending
        for (uint32_t i = 1; i < cc; ++i) {
            uint32_t key = ckeys[i];
            int jj = (int)i - 1;
            while (jj >= 0 && ckeys[jj] < key) { ckeys[jj + 1] = ckeys[jj]; --jj; }
            ckeys[jj + 1] = key;
        }
        s_tkey = (r >= 1 && r <= cc) ? ckeys[r - 1] : 0xFFFFFFFFu;
    }
    __syncthreads();

    const uint32_t tkey = s_tkey;

    // ---- Phase C: write output ----
    for (int it = 0; it < NCOLS / TPB; ++it) {
        uint32_t c = tid + it * TPB;
        uint32_t m = jax_m(base + c);
        uint32_t bin = m >> 10;
        uint32_t key = ((m & 1023u) << 17) | (131071u - c);
        bool zero = (bin > bstar) || (bin == bstar && key >= tkey);
        uint32_t idx = base + c;
        out[idx] = zero ? 0.0f : in[idx];
    }
}

extern "C" void kernel_launch(void* const* d_in, const int* in_sizes, int n_in,
                              void* d_out, int out_size, void* d_ws, size_t ws_size,
                              hipStream_t stream) {
    const float* in = (const float*)d_in[0];
    float* out = (float*)d_out;
    hipLaunchKernelGGL(topk_mask_kernel, dim3(NROWS), dim3(TPB), 0, stream, in, out);
}

// Round 4
// 337.493 us; speedup vs baseline: 1.4359x; 1.4359x over previous
//
#include <hip/hip_runtime.h>
#include <stdint.h>

// reference: rec_audio (256, 131072) f32, k = int(0.03*131072) = 3932
#define NROWS 256
#define NCOLS 131072
#define KSEL  3932
#define TPB   1024
#define BINS  8192          // histogram over top 13 bits of the random word
#define MAXC  512           // boundary-bin candidates (expected ~16 per row)

__device__ __forceinline__ uint32_t rotl32(uint32_t v, int r) {
    return (v << r) | (v >> (32 - r));
}

// JAX threefry2x32, key (0, 42), partitionable scheme:
// counter = (uint64)j -> x0 = 0, x1 = j; bits = out0 ^ out1.  (verified bit-exact, round 1)
__device__ __forceinline__ uint32_t jax_bits(uint32_t j) {
    const uint32_t ks0 = 0u;
    const uint32_t ks1 = 42u;
    const uint32_t ks2 = ks0 ^ ks1 ^ 0x1BD11BDAu;
    uint32_t x0 = 0u + ks0;
    uint32_t x1 = j + ks1;
#define TF_RND(r) { x0 += x1; x1 = rotl32(x1, r); x1 ^= x0; }
    TF_RND(13) TF_RND(15) TF_RND(26) TF_RND(6)
    x0 += ks1; x1 += ks2 + 1u;
    TF_RND(17) TF_RND(29) TF_RND(16) TF_RND(24)
    x0 += ks2; x1 += ks0 + 2u;
    TF_RND(13) TF_RND(15) TF_RND(26) TF_RND(6)
    x0 += ks0; x1 += ks1 + 3u;
    TF_RND(17) TF_RND(29) TF_RND(16) TF_RND(24)
    x0 += ks1; x1 += ks2 + 4u;
    TF_RND(13) TF_RND(15) TF_RND(26) TF_RND(6)
    x0 += ks2; x1 += ks0 + 5u;
#undef TF_RND
    return x0 ^ x1;
}

__global__ __launch_bounds__(TPB) void topk_mask_kernel(const float* __restrict__ in,
                                                        float* __restrict__ out) {
    __shared__ uint32_t hist[BINS];          // 32 KB
    __shared__ uint32_t chunk[TPB];          // 4 KB (chunk sums -> suffix sums)
    __shared__ uint32_t ckeys[MAXC];         // 2 KB
    __shared__ uint32_t s_ccount;
    __shared__ uint32_t s_bstar;
    __shared__ uint32_t s_r;
    __shared__ uint32_t s_tkey;

    const uint32_t row  = blockIdx.x;
    const uint32_t tid  = threadIdx.x;
    const uint32_t base = row * (uint32_t)NCOLS;

    for (uint32_t i = tid; i < BINS; i += TPB) hist[i] = 0u;
    if (tid == 0) s_ccount = 0u;
    __syncthreads();

    // ---- Pass 1: histogram over bits >> 19 (top 13 bits), 4 elems/thread/iter ----
    for (int it = 0; it < NCOLS / (TPB * 4); ++it) {
        uint32_t c = (uint32_t)it * (TPB * 4) + tid * 4;
        #pragma unroll
        for (int e = 0; e < 4; ++e) {
            uint32_t bits = jax_bits(base + c + e);
            atomicAdd(&hist[bits >> 19], 1u);
        }
    }
    __syncthreads();

    // per-thread chunk sums (8 bins each)
    uint32_t cs = 0;
    #pragma unroll
    for (int b = 0; b < BINS / TPB; ++b) cs += hist[tid * (BINS / TPB) + b];
    chunk[tid] = cs;
    __syncthreads();

    // parallel suffix inclusive scan (Hillis-Steele, from the top)
    uint32_t S = cs;
    for (uint32_t off = 1; off < TPB; off <<= 1) {
        uint32_t v = (tid + off < TPB) ? chunk[tid + off] : 0u;
        __syncthreads();
        S += v;
        chunk[tid] = S;
        __syncthreads();
    }

    const uint32_t above = S - cs;   // elements strictly above my chunk
    if (above < KSEL && S >= KSEL) { // boundary bin is in my chunk (exactly one thread)
        uint32_t acc = above;
        for (int b = BINS / TPB - 1; b >= 0; --b) {
            uint32_t bin = tid * (BINS / TPB) + b;
            uint32_t h = hist[bin];
            if (acc < KSEL && acc + h >= KSEL) {
                s_bstar = bin;
                s_r = KSEL - acc;    // how many to take from the boundary bin
            }
            acc += h;
        }
    }
    __syncthreads();

    const uint32_t bstar = s_bstar;
    const uint32_t r     = s_r;

    // ---- Pass 2 (merged): write output, collect boundary-bin candidates ----
    const float4* in4  = (const float4*)(in + base);
    float4*       out4 = (float4*)(out + base);
    for (int it = 0; it < NCOLS / (TPB * 4); ++it) {
        uint32_t vi = (uint32_t)it * TPB + tid;     // float4 index
        uint32_t c  = vi * 4;
        float4 v = in4[vi];
        float* pv = (float*)&v;
        #pragma unroll
        for (int e = 0; e < 4; ++e) {
            uint32_t bits = jax_bits(base + c + e);
            uint32_t bin = bits >> 19;
            if (bin > bstar) {
                pv[e] = 0.0f;
            } else if (bin == bstar) {
                // value-desc, index-asc key (distinct: embeds index). provisional passthrough.
                uint32_t key = (((bits >> 9) & 1023u) << 17) | (131071u - (c + e));
                uint32_t pos = atomicAdd(&s_ccount, 1u);
                if (pos < MAXC) ckeys[pos] = key;
            }
        }
        out4[vi] = v;
    }
    __syncthreads();

    // ---- parallel rank-select of the r-th largest candidate key ----
    uint32_t cc = s_ccount; if (cc > MAXC) cc = MAXC;
    if (tid < cc) {
        uint32_t mykey = ckeys[tid];
        uint32_t rank = 0;
        for (uint32_t i = 0; i < cc; ++i) rank += (ckeys[i] > mykey) ? 1u : 0u;
        if (rank == r - 1) s_tkey = mykey;   // r>=1 and r<=cc guaranteed
    }
    __syncthreads();

    const uint32_t tkey = s_tkey;

    // ---- fixup: zero exactly the r selected boundary-bin elements ----
    if (tid < cc) {
        uint32_t mykey = ckeys[tid];
        if (mykey >= tkey) {
            uint32_t c = 131071u - (mykey & 0x1FFFFu);
            out[base + c] = 0.0f;
        }
    }
}

extern "C" void kernel_launch(void* const* d_in, const int* in_sizes, int n_in,
                              void* d_out, int out_size, void* d_ws, size_t ws_size,
                              hipStream_t stream) {
    const float* in = (const float*)d_in[0];
    float* out = (float*)d_out;
    hipLaunchKernelGGL(topk_mask_kernel, dim3(NROWS), dim3(TPB), 0, stream, in, out);
}

// Round 10
// 309.123 us; speedup vs baseline: 1.5676x; 1.0918x over previous
//
#include <hip/hip_runtime.h>
#include <stdint.h>

// reference: rec_audio (256, 131072) f32, k = int(0.03*131072) = 3932
#define NROWS 256
#define NCOLS 131072
#define KSEL  3932
#define TPB   1024
#define VITERS (NCOLS / (TPB * 4))   // 32 float4-iterations per thread
#define BINS  256                    // histogram over top 8 bits of the random word
#define MAXC  1024                   // boundary-bin candidates (expected ~512, cap 1024 = 22 sigma)

// single-instruction rotate: rotl(v,r) == v_alignbit_b32(v, v, 32-r)
__device__ __forceinline__ uint32_t rotl32(uint32_t v, int r) {
    return __builtin_amdgcn_alignbit(v, v, 32 - r);
}

// JAX threefry2x32, key (0, 42), partitionable scheme:
// counter = (uint64)j -> x0 = 0, x1 = j; bits = out0 ^ out1.  (verified bit-exact, round 1)
__device__ __forceinline__ uint32_t jax_bits(uint32_t j) {
    const uint32_t ks0 = 0u;
    const uint32_t ks1 = 42u;
    const uint32_t ks2 = ks0 ^ ks1 ^ 0x1BD11BDAu;
    uint32_t x0 = 0u + ks0;
    uint32_t x1 = j + ks1;
#define TF_RND(r) { x0 += x1; x1 = rotl32(x1, r); x1 ^= x0; }
    TF_RND(13) TF_RND(15) TF_RND(26) TF_RND(6)
    x0 += ks1; x1 += ks2 + 1u;
    TF_RND(17) TF_RND(29) TF_RND(16) TF_RND(24)
    x0 += ks2; x1 += ks0 + 2u;
    TF_RND(13) TF_RND(15) TF_RND(26) TF_RND(6)
    x0 += ks0; x1 += ks1 + 3u;
    TF_RND(17) TF_RND(29) TF_RND(16) TF_RND(24)
    x0 += ks1; x1 += ks2 + 4u;
    TF_RND(13) TF_RND(15) TF_RND(26) TF_RND(6)
    x0 += ks2; x1 += ks0 + 5u;
#undef TF_RND
    return x0 ^ x1;
}

__global__ __launch_bounds__(TPB) void topk_mask_kernel(const float* __restrict__ in,
                                                        float* __restrict__ out) {
    __shared__ uint32_t hist[BINS];          // 1 KB
    __shared__ uint32_t scanb[BINS];         // 1 KB
    __shared__ uint32_t ckeys[MAXC];         // 4 KB: candidate indices, then candidate keys
    __shared__ uint32_t s_ccount;
    __shared__ uint32_t s_bstar;
    __shared__ uint32_t s_r;
    __shared__ uint32_t s_tkey;

    const uint32_t row  = blockIdx.x;
    const uint32_t tid  = threadIdx.x;
    const uint32_t base = row * (uint32_t)NCOLS;

    // register byte-cache: top byte of each of this thread's 128 elements.
    // grid = 256 blocks = 1 block/CU, so VGPR use doesn't cost occupancy.
    uint32_t pk[VITERS];

    if (tid < BINS) hist[tid] = 0u;
    if (tid == 0) s_ccount = 0u;
    __syncthreads();

    // ---- Pass 1 (the ONLY full threefry pass): histogram + register byte-cache ----
    #pragma unroll
    for (int it = 0; it < VITERS; ++it) {
        uint32_t vi = (uint32_t)it * TPB + tid;
        uint32_t j  = base + vi * 4u;
        uint32_t b0 = jax_bits(j + 0u);
        uint32_t b1 = jax_bits(j + 1u);
        uint32_t b2 = jax_bits(j + 2u);
        uint32_t b3 = jax_bits(j + 3u);
        atomicAdd(&hist[b0 >> 24], 1u);
        atomicAdd(&hist[b1 >> 24], 1u);
        atomicAdd(&hist[b2 >> 24], 1u);
        atomicAdd(&hist[b3 >> 24], 1u);
        pk[it] = (b0 >> 24) | ((b1 >> 24) << 8) | ((b2 >> 24) << 16) | ((b3 >> 24) << 24);
    }
    __syncthreads();

    // ---- suffix scan over 256 bins (Hillis-Steele, 8 steps) ----
    uint32_t h = 0, S = 0;
    if (tid < BINS) { h = hist[tid]; scanb[tid] = h; }
    __syncthreads();
    S = h;
    for (uint32_t off = 1; off < BINS; off <<= 1) {
        uint32_t v = 0;
        if (tid < BINS && tid + off < BINS) v = scanb[tid + off];
        __syncthreads();
        if (tid < BINS) { S += v; scanb[tid] = S; }
        __syncthreads();
    }
    if (tid < BINS) {
        uint32_t above = S - h;            // elements in bins strictly above mine
        if (above < KSEL && S >= KSEL) {   // exactly one thread
            s_bstar = tid;
            s_r = KSEL - above;            // how many to take from the boundary bin
        }
    }
    __syncthreads();

    const uint32_t bstar = s_bstar;
    const uint32_t r     = s_r;

    // ---- Pass 2: classify from cached byte, write output, push candidate indices ----
    const float4* in4  = (const float4*)(in + base);
    float4*       out4 = (float4*)(out + base);
    #pragma unroll
    for (int it = 0; it < VITERS; ++it) {
        uint32_t vi = (uint32_t)it * TPB + tid;
        uint32_t c  = vi * 4u;
        float4 v = in4[vi];
        uint32_t p = pk[it];
        float* pv = (float*)&v;
        #pragma unroll
        for (int e = 0; e < 4; ++e) {
            uint32_t bin = (p >> (8 * e)) & 0xFFu;
            if (bin > bstar) {
                pv[e] = 0.0f;
            } else if (bin == bstar) {
                uint32_t pos = atomicAdd(&s_ccount, 1u);
                if (pos < MAXC) ckeys[pos] = c + (uint32_t)e;   // provisional passthrough
            }
        }
        out4[vi] = v;
    }
    __syncthreads();

    // ---- recompute keys for the ~512 candidates only (one threefry each, parallel) ----
    uint32_t cc = s_ccount; if (cc > MAXC) cc = MAXC;
    uint32_t mykey = 0, myc = 0;
    if (tid < cc) {
        myc = ckeys[tid];
        uint32_t bits = jax_bits(base + myc);
        // value-desc / index-asc total order: 15 residual value bits + 17-bit reversed index
        mykey = (((bits >> 9) & 0x7FFFu) << 17) | (131071u - myc);
    }
    __syncthreads();
    if (tid < cc) ckeys[tid] = mykey;
    __syncthreads();

    // ---- parallel rank-select of the r-th largest candidate key ----
    if (tid < cc) {
        uint32_t rank = 0;
        for (uint32_t i = 0; i < cc; ++i) rank += (ckeys[i] > mykey) ? 1u : 0u;
        if (rank == r - 1) s_tkey = mykey;   // keys distinct -> exactly one writer
    }
    __syncthreads();

    // ---- fixup: zero exactly the r selected boundary-bin elements ----
    if (tid < cc && mykey >= s_tkey) {
        out[base + myc] = 0.0f;
    }
}

extern "C" void kernel_launch(void* const* d_in, const int* in_sizes, int n_in,
                              void* d_out, int out_size, void* d_ws, size_t ws_size,
                              hipStream_t stream) {
    const float* in = (const float*)d_in[0];
    float* out = (float*)d_out;
    hipLaunchKernelGGL(topk_mask_kernel, dim3(NROWS), dim3(TPB), 0, stream, in, out);
}

// Round 11
// 295.875 us; speedup vs baseline: 1.6378x; 1.0448x over previous
//
#include <hip/hip_runtime.h>
#include <stdint.h>

// reference: rec_audio (256, 131072) f32, k = int(0.03*131072) = 3932
#define NROWS 256
#define NCOLS 131072
#define KSEL  3932
#define TPB   1024
#define VITERS (NCOLS / (TPB * 4))   // 32 float4-iterations per thread
// Candidate threshold on m = bits>>9 (23-bit). p = (2^23-TM)/2^23 = 0.033582
// -> mean candidates/row = 4401, sigma = 65. KSEL=3932 is 7.2 sigma below,
// MAXC=5120 is 11 sigma above. Deterministic stream -> if it passes once, always.
#define TM    8106908u
#define MAXC  5120
#define SBINS 256                    // selection histogram: bin = (m-TM)>>11, max bin 137
#define MAXB  256                    // boundary-bin capacity (mean ~32)

// single-instruction rotate: rotl(v,r) == v_alignbit_b32(v, v, 32-r)
__device__ __forceinline__ uint32_t rotl32(uint32_t v, int r) {
    return __builtin_amdgcn_alignbit(v, v, 32 - r);
}

// JAX threefry2x32, key (0, 42), partitionable scheme:
// counter = (uint64)j -> x0 = 0, x1 = j; bits = out0 ^ out1.  (verified bit-exact, round 1)
__device__ __forceinline__ uint32_t jax_bits(uint32_t j) {
    const uint32_t ks0 = 0u;
    const uint32_t ks1 = 42u;
    const uint32_t ks2 = ks0 ^ ks1 ^ 0x1BD11BDAu;
    uint32_t x0 = 0u + ks0;
    uint32_t x1 = j + ks1;
#define TF_RND(r) { x0 += x1; x1 = rotl32(x1, r); x1 ^= x0; }
    TF_RND(13) TF_RND(15) TF_RND(26) TF_RND(6)
    x0 += ks1; x1 += ks2 + 1u;
    TF_RND(17) TF_RND(29) TF_RND(16) TF_RND(24)
    x0 += ks2; x1 += ks0 + 2u;
    TF_RND(13) TF_RND(15) TF_RND(26) TF_RND(6)
    x0 += ks0; x1 += ks1 + 3u;
    TF_RND(17) TF_RND(29) TF_RND(16) TF_RND(24)
    x0 += ks1; x1 += ks2 + 4u;
    TF_RND(13) TF_RND(15) TF_RND(26) TF_RND(6)
    x0 += ks2; x1 += ks0 + 5u;
#undef TF_RND
    return x0 ^ x1;
}

__global__ __launch_bounds__(TPB) void topk_mask_kernel(const float* __restrict__ in,
                                                        float* __restrict__ out) {
    __shared__ uint32_t cm[MAXC];     // 20 KB: candidate m - TM (19 bits)
    __shared__ uint32_t cidx[MAXC];   // 20 KB: candidate column index
    __shared__ uint32_t hist[SBINS];  // 1 KB
    __shared__ uint32_t scanb[SBINS]; // 1 KB
    __shared__ uint32_t bkeys[MAXB];  // 1 KB: boundary-bin keys
    __shared__ uint32_t s_ccount;
    __shared__ uint32_t s_bcnt;
    __shared__ uint32_t s_bstar;
    __shared__ uint32_t s_r;
    __shared__ uint32_t s_tkey;

    const uint32_t row  = blockIdx.x;
    const uint32_t tid  = threadIdx.x;
    const uint32_t base = row * (uint32_t)NCOLS;

    if (tid < SBINS) hist[tid] = 0u;
    if (tid == 0) { s_ccount = 0u; s_bcnt = 0u; }
    __syncthreads();

    // ---- Pass 1: threefry + fused copy + candidate push (the only full sweep) ----
    const float4* in4  = (const float4*)(in + base);
    float4*       out4 = (float4*)(out + base);
    for (int it = 0; it < VITERS; ++it) {
        uint32_t vi = (uint32_t)it * TPB + tid;
        uint32_t c  = vi * 4u;
        uint32_t j  = base + c;
        float4 v = in4[vi];                    // issue load early; latency hides under threefry
        uint32_t m0 = jax_bits(j + 0u) >> 9;
        uint32_t m1 = jax_bits(j + 1u) >> 9;
        uint32_t m2 = jax_bits(j + 2u) >> 9;
        uint32_t m3 = jax_bits(j + 3u) >> 9;
        out4[vi] = v;                          // provisional passthrough copy
        if (m0 >= TM) { uint32_t p = atomicAdd(&s_ccount, 1u); if (p < MAXC) { cm[p] = m0 - TM; cidx[p] = c + 0u; } }
        if (m1 >= TM) { uint32_t p = atomicAdd(&s_ccount, 1u); if (p < MAXC) { cm[p] = m1 - TM; cidx[p] = c + 1u; } }
        if (m2 >= TM) { uint32_t p = atomicAdd(&s_ccount, 1u); if (p < MAXC) { cm[p] = m2 - TM; cidx[p] = c + 2u; } }
        if (m3 >= TM) { uint32_t p = atomicAdd(&s_ccount, 1u); if (p < MAXC) { cm[p] = m3 - TM; cidx[p] = c + 3u; } }
    }
    __syncthreads();

    uint32_t cc = s_ccount; if (cc > MAXC) cc = MAXC;

    // ---- Selection phase (all on ~4400 candidates) ----
    // histogram over candidate bins
    for (uint32_t i = tid; i < cc; i += TPB) atomicAdd(&hist[cm[i] >> 11], 1u);
    __syncthreads();

    // suffix scan over 256 bins (Hillis-Steele, 8 steps)
    uint32_t h = 0, S = 0;
    if (tid < SBINS) { h = hist[tid]; scanb[tid] = h; }
    __syncthreads();
    S = h;
    for (uint32_t off = 1; off < SBINS; off <<= 1) {
        uint32_t v = 0;
        if (tid < SBINS && tid + off < SBINS) v = scanb[tid + off];
        __syncthreads();
        if (tid < SBINS) { S += v; scanb[tid] = S; }
        __syncthreads();
    }
    if (tid < SBINS) {
        uint32_t above = S - h;            // candidates in bins strictly above mine
        if (above < KSEL && S >= KSEL) {   // exactly one thread
            s_bstar = tid;
            s_r = KSEL - above;            // how many to take from the boundary bin
        }
    }
    __syncthreads();

    const uint32_t bstar = s_bstar;
    const uint32_t r     = s_r;

    // gather boundary-bin keys (value-desc / index-asc total order, 28 bits, distinct)
    for (uint32_t i = tid; i < cc; i += TPB) {
        if ((cm[i] >> 11) == bstar) {
            uint32_t p = atomicAdd(&s_bcnt, 1u);
            if (p < MAXB) bkeys[p] = ((cm[i] & 2047u) << 17) | (131071u - cidx[i]);
        }
    }
    __syncthreads();

    uint32_t bc = s_bcnt; if (bc > MAXB) bc = MAXB;
    if (tid < bc) {
        uint32_t mykey = bkeys[tid];
        uint32_t rank = 0;
        for (uint32_t i = 0; i < bc; ++i) rank += (bkeys[i] > mykey) ? 1u : 0u;
        if (rank == r - 1) s_tkey = mykey;   // keys distinct -> exactly one writer
    }
    __syncthreads();

    const uint32_t tkey = s_tkey;

    // ---- Pass 3: scatter zeros (exactly KSEL elements per row) ----
    for (uint32_t i = tid; i < cc; i += TPB) {
        uint32_t bin = cm[i] >> 11;
        bool z = (bin > bstar);
        if (bin == bstar) {
            uint32_t key = ((cm[i] & 2047u) << 17) | (131071u - cidx[i]);
            z = (key >= tkey);
        }
        if (z) out[base + cidx[i]] = 0.0f;
    }
}

extern "C" void kernel_launch(void* const* d_in, const int* in_sizes, int n_in,
                              void* d_out, int out_size, void* d_ws, size_t ws_size,
                              hipStream_t stream) {
    const float* in = (const float*)d_in[0];
    float* out = (float*)d_out;
    hipLaunchKernelGGL(topk_mask_kernel, dim3(NROWS), dim3(TPB), 0, stream, in, out);
}